// Round 18
// baseline (65.325 us; speedup 1.0000x reference)
//
#include <hip/hip_runtime.h>

#define HH 128
#define WW 128
#define CC 64
#define OCC 64
#define BB 8
#define NPIX (BB * HH * WW)   // 131072
#define PXB 128               // pixels per fused block (2 rows x 64 cols)

typedef __attribute__((ext_vector_type(4))) float f32x4;
typedef __attribute__((ext_vector_type(2))) float f32x2;
typedef __attribute__((ext_vector_type(8))) short bf16x8;
typedef __attribute__((ext_vector_type(4))) unsigned u32x4;

// ---- ws layout (full path) ----
#define XT_OFF 0                         // xt [B][H][W][C] bf16 = 16,777,216 B
#define W1F_OFF 16777216                 // w1f [2][18][64][8] bf16 = 36,864 B
#define W2F_OFF 16814080                 // w2f [4][18][64][8] bf16 = 73,728 B
#define WS_FULL (16814080 + 73728)

// window: 5 rows (oh0-1..oh0+3) x 66 cols (ow0-1..ow0+64) x 64ch bf16
// (swizzled), serving a 2-row x 64-col pixel block (128 px, 512 threads).
// Dynamic LDS: 42,240 + 128*72*4 = 79,104 B -> 2 blocks/CU.  [R17 verified]
#define WROWS 5
#define WCOLS 66
#define WIN_BYTES (WROWS * WCOLS * 128)    // 42240
#define WLDS_STRIDE 72
#define WLDS_FLOATS (PXB * WLDS_STRIDE)    // 9216 floats = 36864 B
#define SH_TOTAL (WIN_BYTES + WLDS_FLOATS * 4)   // 79104

__device__ __forceinline__ short f2bf(float f) {
    union { float f; unsigned u; } v; v.f = f;
    unsigned r = v.u + 0x7FFF + ((v.u >> 16) & 1);   // RNE
    return (short)(r >> 16);
}

__device__ __forceinline__ unsigned cvtpk_bf16(float lo, float hi) {
    unsigned r;
    asm("v_cvt_pk_bf16_f32 %0, %1, %2" : "=v"(r) : "v"(lo), "v"(hi));
    return r;
}

// Packed bilinear: 8 channels from 4 corner fragments, weights w[0..3].
__device__ __forceinline__ bf16x8 bilerp8(bf16x8 r00, bf16x8 r01, bf16x8 r10, bf16x8 r11,
                                          f32x4 w) {
    u32x4 u00 = __builtin_bit_cast(u32x4, r00);
    u32x4 u01 = __builtin_bit_cast(u32x4, r01);
    u32x4 u10 = __builtin_bit_cast(u32x4, r10);
    u32x4 u11 = __builtin_bit_cast(u32x4, r11);
    u32x4 res;
#pragma unroll
    for (int j = 0; j < 4; j++) {
        f32x2 a, acc;
        a[0] = __builtin_bit_cast(float, (unsigned)(u00[j] << 16));
        a[1] = __builtin_bit_cast(float, (unsigned)(u00[j] & 0xFFFF0000u));
        acc = a * w[0];
        a[0] = __builtin_bit_cast(float, (unsigned)(u01[j] << 16));
        a[1] = __builtin_bit_cast(float, (unsigned)(u01[j] & 0xFFFF0000u));
        acc += a * w[1];
        a[0] = __builtin_bit_cast(float, (unsigned)(u10[j] << 16));
        a[1] = __builtin_bit_cast(float, (unsigned)(u10[j] & 0xFFFF0000u));
        acc += a * w[2];
        a[0] = __builtin_bit_cast(float, (unsigned)(u11[j] << 16));
        a[1] = __builtin_bit_cast(float, (unsigned)(u11[j] & 0xFFFF0000u));
        acc += a * w[3];
        res[j] = cvtpk_bf16(acc[0], acc[1]);
    }
    return __builtin_bit_cast(bf16x8, res);
}

// ---------------- K0: merged weight-pack + NCHW->NHWC transpose ----------------
__global__ __launch_bounds__(256) void prep_and_transpose(
    const float* __restrict__ x, unsigned short* __restrict__ xt,
    const float* __restrict__ weight,
    const float* __restrict__ offset_w,
    const float* __restrict__ mask_w,
    short* __restrict__ w1f, short* __restrict__ w2f) {
    __shared__ float lds[128 * 65];
    int bid = blockIdx.x;
    if (bid < BB * HH) {
        int bh = bid;                  // b*128 + h
        int b = bh >> 7, h = bh & 127;
        const float* xr = x + ((size_t)b * CC * HH + h) * WW;
        int tid = threadIdx.x;
#pragma unroll
        for (int it = 0; it < 32; it++) {
            int e = it * 256 + tid;
            int c = e >> 7, w = e & 127;
            lds[w * 65 + c] = xr[(size_t)c * HH * WW + w];
        }
        __syncthreads();
        unsigned* otr = (unsigned*)(xt + (size_t)bh * WW * CC);   // packed bf16 pairs
#pragma unroll
        for (int it = 0; it < 16; it++) {
            int e = it * 256 + tid;            // pair index: w*32 + cp
            int w = e >> 5, cp = e & 31;
            unsigned lo = (unsigned short)f2bf(lds[w * 65 + 2 * cp]);
            unsigned hi = (unsigned short)f2bf(lds[w * 65 + 2 * cp + 1]);
            otr[e] = lo | (hi << 16);
        }
    } else {
        int tid = (bid - BB * HH) * 256 + threadIdx.x;
        if (tid < 2 * 18 * 64 * 8) {                 // 18432
            int i = tid & 7, lane = (tid >> 3) & 63, ch = (tid >> 9) % 18, tile = tid / (18 * 512);
            int r = tile * 16 + (lane & 15);
            int q = ch * 32 + ((lane >> 4) << 3) + i;
            int k = q >> 6, c = q & 63;
            float v = 0.f;
            if (r < 18)      v = offset_w[(r * CC + c) * 9 + k];
            else if (r < 27) v = mask_w[((r - 18) * CC + c) * 9 + k];
            w1f[tid] = f2bf(v);
        } else {
            int u = tid - 18432;
            if (u < 4 * 18 * 64 * 8) {               // 36864
                int i = u & 7, lane = (u >> 3) & 63, ch = (u >> 9) % 18, tile = u / (18 * 512);
                int oc = tile * 16 + (lane & 15);
                int q = ch * 32 + ((lane >> 4) << 3) + i;
                int k = q >> 6, c = q & 63;
                w2f[u] = f2bf(weight[(oc * CC + c) * 9 + k]);
            }
        }
    }
}

// ---------------- K1: fused conv + deformable einsum, 2-row LDS window ----------------
// [R17 verified body; the ONLY delta is s_setprio(1)/(0) around Phase-B MFMAs]
__global__ __launch_bounds__(512, 4) void fused_mfma(
    const unsigned short* __restrict__ xt,
    const float* __restrict__ offset_b,
    const float* __restrict__ mask_b,
    const float* __restrict__ bias,
    const short* __restrict__ w1f,
    const short* __restrict__ w2f,
    float* __restrict__ out) {
    extern __shared__ __align__(16) char shbuf[];    // SH_TOTAL = 79104 B dynamic
    char* win = shbuf;
    float* wlds = (float*)(shbuf + WIN_BYTES);   // [pl][72]: 9 taps x {4 w, 4 off}
    float* colds = wlds;                         // overlaid [pl][33] (phase A only)

    int lane = threadIdx.x & 63;
    int wv = threadIdx.x >> 6;                    // 0..7
    int bid = blockIdx.x;
    int logical = (bid & 7) * 128 + (bid >> 3);   // XCD-chunked: bid%8 -> image
    int col = lane & 15;
    int qg = lane >> 4;
    int pl = wv * 16 + col;                       // 0..127
    int b = logical >> 7;
    int rem = logical & 127;
    int oh0 = (rem >> 1) << 1;                    // 2-row block
    int ow0 = (rem & 1) << 6;                     // 64-col half
    int oh = oh0 + (pl >> 6);
    int ow = ow0 + (pl & 63);
    const unsigned short* xb = xt + (size_t)b * CC * HH * WW;   // NHWC bf16

    int ylo = max(0, oh0 - 1), yhi = min(HH - 1, oh0 + 3);
    int xlo = max(0, ow0 - 1), xhi = min(WW - 1, ow0 + 64);
    int R = yhi - ylo + 1, C = xhi - xlo + 1;     // R<=5, C<=65

    // ---- Stage window: R x C pixels x 128B, coalesced in, swizzled to LDS
    {
        int C8 = C * 8;
        for (int ry = 0; ry < R; ry++) {
            const unsigned short* src = xb + ((size_t)(ylo + ry) * WW + xlo) * CC;
            for (int t = threadIdx.x; t < C8; t += 512) {
                int rx = t >> 3, s = t & 7;
                u32x4 v = *(const u32x4*)(src + rx * CC + s * 8);
                int pix = ry * WCOLS + rx;
                *(u32x4*)(win + (pix << 7) + ((s ^ (pix & 7)) << 4)) = v;
            }
        }
    }
    __syncthreads();

    // ---- Phase A: 3x3 conv -> 27 offset/mask channels (taps read from window)
    {
        f32x4 acc0 = {0.f,0.f,0.f,0.f}, acc1 = {0.f,0.f,0.f,0.f};
#pragma unroll
        for (int ch = 0; ch < 18; ch++) {
            int k = ch >> 1;
            int iy = oh - 1 + k / 3;
            int ix = ow - 1 + (k - (k / 3) * 3);
            bool vv = (iy >= 0) && (iy < HH) && (ix >= 0) && (ix < WW);
            bf16x8 bfr = {0,0,0,0,0,0,0,0};
            if (vv) {
                int pix = (iy - ylo) * WCOLS + (ix - xlo);
                int s = ((ch & 1) << 2) + qg;
                bfr = *(const bf16x8*)(win + (pix << 7) + (((s ^ pix) & 7) << 4 | (s & ~7) << 4));
            }
            // NOTE: identical addressing to R17: ((s ^ (pix & 7)) << 4) since s<8.
            bfr = bfr;
            if (vv) {
                int pix = (iy - ylo) * WCOLS + (ix - xlo);
                int s = ((ch & 1) << 2) + qg;
                bfr = *(const bf16x8*)(win + (pix << 7) + ((s ^ (pix & 7)) << 4));
            }
            bf16x8 a0 = *(const bf16x8*)(w1f + ((size_t)(0 * 18 + ch) * 64 + lane) * 8);
            bf16x8 a1 = *(const bf16x8*)(w1f + ((size_t)(1 * 18 + ch) * 64 + lane) * 8);
            acc0 = __builtin_amdgcn_mfma_f32_16x16x32_bf16(a0, bfr, acc0, 0, 0, 0);
            acc1 = __builtin_amdgcn_mfma_f32_16x16x32_bf16(a1, bfr, acc1, 0, 0, 0);
        }
#pragma unroll
        for (int j = 0; j < 4; j++) {
            int r0 = (qg << 2) + j;
            int r1 = 16 + r0;
            float b1 = (r1 < 18) ? offset_b[r1] : (r1 < 27 ? mask_b[r1 - 18] : 0.f);
            colds[pl * 33 + r0] = acc0[j] + offset_b[r0];
            colds[pl * 33 + r1] = acc1[j] + b1;
        }
    }
    __syncthreads();

    // ---- Hoist (qg-split): taps k = qg, qg+4, qg+8; read colds now, store later
    float hw[3][4];
    unsigned ho[3][4];
    {
        const float* cop = &colds[pl * 33];
#pragma unroll
        for (int ki = 0; ki < 3; ki++) {
            int k = qg + ki * 4;
            if (k < 9) {
                float dy = cop[2 * k];
                float dx = cop[2 * k + 1];
                float mr = cop[18 + k];
                float m = 1.f / (1.f + __expf(-mr));
                float py = (float)(oh - 1 + k / 3) + dy;
                float px = (float)(ow - 1 + (k - (k / 3) * 3)) + dx;
                float y0f = floorf(py), x0f = floorf(px);
                float fy = py - y0f, fx = px - x0f;
                int y0 = (int)y0f, x0 = (int)x0f;
                int y1 = y0 + 1, x1 = x0 + 1;
                bool vy0 = (y0 >= 0) && (y0 < HH), vy1 = (y1 >= 0) && (y1 < HH);
                bool vx0 = (x0 >= 0) && (x0 < WW), vx1 = (x1 >= 0) && (x1 < WW);
                hw[ki][0] = (vy0 && vx0) ? (1.f - fy) * (1.f - fx) * m : 0.f;
                hw[ki][1] = (vy0 && vx1) ? (1.f - fy) * fx * m : 0.f;
                hw[ki][2] = (vy1 && vx0) ? fy * (1.f - fx) * m : 0.f;
                hw[ki][3] = (vy1 && vx1) ? fy * fx * m : 0.f;
                int iy0 = min(max(y0, 0), HH - 1), iy1 = min(max(y1, 0), HH - 1);
                int ix0 = min(max(x0, 0), WW - 1), ix1 = min(max(x1, 0), WW - 1);
                int wy0 = iy0 - ylo, wy1 = iy1 - ylo;
                int wx0 = ix0 - xlo, wx1 = ix1 - xlo;
                bool fast = (wy0 >= 0) && (wy1 < R) && (wx0 >= 0) && (wx1 < C);
                if (fast) {
                    ho[ki][0] = (unsigned)((wy0 * WCOLS + wx0) << 7);
                    ho[ki][1] = (unsigned)((wy0 * WCOLS + wx1) << 7);
                    ho[ki][2] = (unsigned)((wy1 * WCOLS + wx0) << 7);
                    ho[ki][3] = (unsigned)((wy1 * WCOLS + wx1) << 7);
                } else {
                    ho[ki][0] = (unsigned)((iy0 * WW + ix0) * CC) | 0x80000000u;
                    ho[ki][1] = (unsigned)((iy0 * WW + ix1) * CC) | 0x80000000u;
                    ho[ki][2] = (unsigned)((iy1 * WW + ix0) * CC) | 0x80000000u;
                    ho[ki][3] = (unsigned)((iy1 * WW + ix1) * CC) | 0x80000000u;
                }
            }
        }
    }
    __syncthreads();   // all colds reads done; safe to overwrite with wlds
#pragma unroll
    for (int ki = 0; ki < 3; ki++) {
        int k = qg + ki * 4;
        if (k < 9) {
            float* q = &wlds[pl * WLDS_STRIDE + k * 8];
            q[0] = hw[ki][0]; q[1] = hw[ki][1]; q[2] = hw[ki][2]; q[3] = hw[ki][3];
            ((unsigned*)q)[4] = ho[ki][0]; ((unsigned*)q)[5] = ho[ki][1];
            ((unsigned*)q)[6] = ho[ki][2]; ((unsigned*)q)[7] = ho[ki][3];
        }
    }
    __syncthreads();

    // ---- Phase B: 9 taps, corners from LDS window (outside-window -> global slow path)
    f32x4 acc0 = {0.f,0.f,0.f,0.f}, acc1 = {0.f,0.f,0.f,0.f};
    f32x4 acc2 = {0.f,0.f,0.f,0.f}, acc3 = {0.f,0.f,0.f,0.f};
    const float* wp = &wlds[pl * WLDS_STRIDE];
    const unsigned short* xq = xb + (qg << 3);
    unsigned sh0 = (unsigned)(qg << 4);
    unsigned sh1 = sh0 + 64;

#pragma unroll
    for (int k = 0; k < 9; k++) {
        f32x4 wq = *(const f32x4*)(wp + k * 8);
        u32x4 o = __builtin_bit_cast(u32x4, *(const f32x4*)(wp + k * 8 + 4));
        bf16x8 h0[4], h1[4];
        if (!(o[0] & 0x80000000u)) {
#pragma unroll
            for (int c = 0; c < 4; c++) {
                unsigned base = o[c];
                unsigned swz = (base >> 3) & 0x70;
                h0[c] = *(const bf16x8*)(win + base + (sh0 ^ swz));
                h1[c] = *(const bf16x8*)(win + base + (sh1 ^ swz));
            }
        } else {
#pragma unroll
            for (int c = 0; c < 4; c++) {
                unsigned off = o[c] & 0x7FFFFFFFu;
                h0[c] = *(const bf16x8*)(xq + off);
                h1[c] = *(const bf16x8*)(xq + off + 32);
            }
        }
        bf16x8 bf0 = bilerp8(h0[0], h0[1], h0[2], h0[3], wq);
        bf16x8 bf1 = bilerp8(h1[0], h1[1], h1[2], h1[3], wq);
        __builtin_amdgcn_s_setprio(1);
#pragma unroll
        for (int h = 0; h < 2; h++) {
            bf16x8 bfr = h ? bf1 : bf0;
            int ch = 2 * k + h;
            const short* ap = w2f + ((size_t)ch * 64 + lane) * 8;
            bf16x8 a0 = *(const bf16x8*)(ap);
            bf16x8 a1 = *(const bf16x8*)(ap + 18 * 512);
            bf16x8 a2 = *(const bf16x8*)(ap + 36 * 512);
            bf16x8 a3 = *(const bf16x8*)(ap + 54 * 512);
            acc0 = __builtin_amdgcn_mfma_f32_16x16x32_bf16(a0, bfr, acc0, 0, 0, 0);
            acc1 = __builtin_amdgcn_mfma_f32_16x16x32_bf16(a1, bfr, acc1, 0, 0, 0);
            acc2 = __builtin_amdgcn_mfma_f32_16x16x32_bf16(a2, bfr, acc2, 0, 0, 0);
            acc3 = __builtin_amdgcn_mfma_f32_16x16x32_bf16(a3, bfr, acc3, 0, 0, 0);
        }
        __builtin_amdgcn_s_setprio(0);
    }

    size_t ob = (size_t)b * OCC * HH * WW + (size_t)oh * WW + ow;
#pragma unroll
    for (int j = 0; j < 4; j++) {
        int r = (qg << 2) + j;
        out[ob + (size_t)r * HH * WW]        = acc0[j] + bias[r];
        out[ob + (size_t)(r + 16) * HH * WW] = acc1[j] + bias[r + 16];
        out[ob + (size_t)(r + 32) * HH * WW] = acc2[j] + bias[r + 32];
        out[ob + (size_t)(r + 48) * HH * WW] = acc3[j] + bias[r + 48];
    }
}

// ---------------- Fallback (round-1, all-f32, no ws) ----------------
__global__ __launch_bounds__(256)
void deform_fused_fb(const float* __restrict__ x,
                     const float* __restrict__ weight,
                     const float* __restrict__ bias,
                     const float* __restrict__ offset_w,
                     const float* __restrict__ offset_b,
                     const float* __restrict__ mask_w,
                     const float* __restrict__ mask_b,
                     float* __restrict__ out) {
    int p = blockIdx.x * 256 + threadIdx.x;
    int ow = p & (WW - 1);
    int oh = (p >> 7) & (HH - 1);
    int b = p >> 14;
    const float* xb = x + (size_t)b * CC * HH * WW;

    float acc[27];
#pragma unroll
    for (int j = 0; j < 18; j++) acc[j] = offset_b[j];
#pragma unroll
    for (int j = 0; j < 9; j++) acc[18 + j] = mask_b[j];

    for (int c = 0; c < CC; c++) {
        const float* xc = xb + c * HH * WW;
        float xv[9];
#pragma unroll
        for (int t = 0; t < 9; t++) {
            int iy = oh - 1 + t / 3;
            int ix = ow - 1 + t % 3;
            bool v = (iy >= 0) && (iy < HH) && (ix >= 0) && (ix < WW);
            xv[t] = v ? xc[iy * WW + ix] : 0.f;
        }
#pragma unroll
        for (int t = 0; t < 9; t++)
#pragma unroll
            for (int j = 0; j < 27; j++) {
                float wv = (j < 18) ? offset_w[(j * CC + c) * 9 + t]
                                    : mask_w[((j - 18) * CC + c) * 9 + t];
                acc[j] += xv[t] * wv;
            }
    }

    float acc2[OCC];
#pragma unroll
    for (int o = 0; o < OCC; o++) acc2[o] = 0.f;

#pragma unroll
    for (int k = 0; k < 9; k++) {
        float dy = acc[2 * k], dx = acc[2 * k + 1];
        float m = 1.f / (1.f + __expf(-acc[18 + k]));
        float py = (float)(oh - 1 + k / 3) + dy;
        float px = (float)(ow - 1 + k % 3) + dx;
        float y0f = floorf(py), x0f = floorf(px);
        float fy = py - y0f, fx = px - x0f;
        int y0 = (int)y0f, x0 = (int)x0f;
        int y1 = y0 + 1, x1 = x0 + 1;
        bool vy0 = (y0 >= 0) && (y0 < HH), vy1 = (y1 >= 0) && (y1 < HH);
        bool vx0 = (x0 >= 0) && (x0 < WW), vx1 = (x1 >= 0) && (x1 < WW);
        float w00 = (vy0 && vx0) ? (1.f - fy) * (1.f - fx) * m : 0.f;
        float w01 = (vy0 && vx1) ? (1.f - fy) * fx * m : 0.f;
        float w10 = (vy1 && vx0) ? fy * (1.f - fx) * m : 0.f;
        float w11 = (vy1 && vx1) ? fy * fx * m : 0.f;
        int iy0 = min(max(y0, 0), HH - 1), iy1 = min(max(y1, 0), HH - 1);
        int ix0 = min(max(x0, 0), WW - 1), ix1 = min(max(x1, 0), WW - 1);
        int o00 = iy0 * WW + ix0, o01 = iy0 * WW + ix1;
        int o10 = iy1 * WW + ix0, o11 = iy1 * WW + ix1;
        for (int c = 0; c < CC; c++) {
            const float* xc = xb + c * HH * WW;
            float v = w00 * xc[o00] + w01 * xc[o01] + w10 * xc[o10] + w11 * xc[o11];
#pragma unroll
            for (int o = 0; o < OCC; o++) acc2[o] += v * weight[(o * CC + c) * 9 + k];
        }
    }
    float* ob = out + (size_t)b * OCC * HH * WW + oh * WW + ow;
#pragma unroll
    for (int o = 0; o < OCC; o++) ob[(size_t)o * HH * WW] = acc2[o] + bias[o];
}

extern "C" void kernel_launch(void* const* d_in, const int* in_sizes, int n_in,
                              void* d_out, int out_size, void* d_ws, size_t ws_size,
                              hipStream_t stream) {
    const float* x        = (const float*)d_in[0];
    const float* weight   = (const float*)d_in[1];
    const float* bias     = (const float*)d_in[2];
    const float* offset_w = (const float*)d_in[3];
    const float* offset_b = (const float*)d_in[4];
    const float* mask_w   = (const float*)d_in[5];
    const float* mask_b   = (const float*)d_in[6];
    float* out = (float*)d_out;

    if (ws_size >= (size_t)WS_FULL) {
        unsigned short* xt = (unsigned short*)((char*)d_ws + XT_OFF);
        short* w1f = (short*)((char*)d_ws + W1F_OFF);
        short* w2f = (short*)((char*)d_ws + W2F_OFF);
        (void)hipFuncSetAttribute((const void*)fused_mfma,
                                  hipFuncAttributeMaxDynamicSharedMemorySize, SH_TOTAL);
        prep_and_transpose<<<BB * HH + 216, 256, 0, stream>>>(x, xt, weight, offset_w,
                                                              mask_w, w1f, w2f);
        fused_mfma<<<NPIX / PXB, 512, SH_TOTAL, stream>>>(xt, offset_b, mask_b, bias,
                                                          w1f, w2f, out);
    } else {
        deform_fused_fb<<<NPIX / 256, 256, 0, stream>>>(x, weight, bias, offset_w, offset_b,
                                                        mask_w, mask_b, out);
    }
}

// Round 19
// 62.175 us; speedup vs baseline: 1.0507x; 1.0507x over previous
//
#include <hip/hip_runtime.h>

#define HH 128
#define WW 128
#define CC 64
#define OCC 64
#define BB 8
#define NPIX (BB * HH * WW)   // 131072
#define PXB 128               // pixels per fused block (2 rows x 64 cols)

typedef __attribute__((ext_vector_type(4))) float f32x4;
typedef __attribute__((ext_vector_type(2))) float f32x2;
typedef __attribute__((ext_vector_type(8))) short bf16x8;
typedef __attribute__((ext_vector_type(4))) unsigned u32x4;

// ---- ws layout (full path) ----
#define XT_OFF 0                         // xt [B][H][W][C] bf16 = 16,777,216 B
#define W1F_OFF 16777216                 // w1f [2][18][64][8] bf16 = 36,864 B
#define W2F_OFF 16814080                 // w2f [4][18][64][8] bf16 = 73,728 B
#define WS_FULL (16814080 + 73728)

// window: 5 rows (oh0-1..oh0+3) x 66 cols (ow0-1..ow0+64) x 64ch bf16
// (swizzled), serving a 2-row x 64-col pixel block (128 px, 512 threads).
// Dynamic LDS: 42,240 + 128*72*4 = 79,104 B -> 2 blocks/CU.  [R17 verified]
#define WROWS 5
#define WCOLS 66
#define WIN_BYTES (WROWS * WCOLS * 128)    // 42240
#define WLDS_STRIDE 72
#define WLDS_FLOATS (PXB * WLDS_STRIDE)    // 9216 floats = 36864 B
#define SH_TOTAL (WIN_BYTES + WLDS_FLOATS * 4)   // 79104

__device__ __forceinline__ short f2bf(float f) {
    union { float f; unsigned u; } v; v.f = f;
    unsigned r = v.u + 0x7FFF + ((v.u >> 16) & 1);   // RNE
    return (short)(r >> 16);
}

__device__ __forceinline__ unsigned cvtpk_bf16(float lo, float hi) {
    unsigned r;
    asm("v_cvt_pk_bf16_f32 %0, %1, %2" : "=v"(r) : "v"(lo), "v"(hi));
    return r;
}

// Packed bilinear: 8 channels from 4 corner fragments, weights w[0..3].
__device__ __forceinline__ bf16x8 bilerp8(bf16x8 r00, bf16x8 r01, bf16x8 r10, bf16x8 r11,
                                          f32x4 w) {
    u32x4 u00 = __builtin_bit_cast(u32x4, r00);
    u32x4 u01 = __builtin_bit_cast(u32x4, r01);
    u32x4 u10 = __builtin_bit_cast(u32x4, r10);
    u32x4 u11 = __builtin_bit_cast(u32x4, r11);
    u32x4 res;
#pragma unroll
    for (int j = 0; j < 4; j++) {
        f32x2 a, acc;
        a[0] = __builtin_bit_cast(float, (unsigned)(u00[j] << 16));
        a[1] = __builtin_bit_cast(float, (unsigned)(u00[j] & 0xFFFF0000u));
        acc = a * w[0];
        a[0] = __builtin_bit_cast(float, (unsigned)(u01[j] << 16));
        a[1] = __builtin_bit_cast(float, (unsigned)(u01[j] & 0xFFFF0000u));
        acc += a * w[1];
        a[0] = __builtin_bit_cast(float, (unsigned)(u10[j] << 16));
        a[1] = __builtin_bit_cast(float, (unsigned)(u10[j] & 0xFFFF0000u));
        acc += a * w[2];
        a[0] = __builtin_bit_cast(float, (unsigned)(u11[j] << 16));
        a[1] = __builtin_bit_cast(float, (unsigned)(u11[j] & 0xFFFF0000u));
        acc += a * w[3];
        res[j] = cvtpk_bf16(acc[0], acc[1]);
    }
    return __builtin_bit_cast(bf16x8, res);
}

// ---------------- K0: merged weight-pack + NCHW->NHWC transpose ----------------
__global__ __launch_bounds__(256) void prep_and_transpose(
    const float* __restrict__ x, unsigned short* __restrict__ xt,
    const float* __restrict__ weight,
    const float* __restrict__ offset_w,
    const float* __restrict__ mask_w,
    short* __restrict__ w1f, short* __restrict__ w2f) {
    __shared__ float lds[128 * 65];
    int bid = blockIdx.x;
    if (bid < BB * HH) {
        int bh = bid;                  // b*128 + h
        int b = bh >> 7, h = bh & 127;
        const float* xr = x + ((size_t)b * CC * HH + h) * WW;
        int tid = threadIdx.x;
#pragma unroll
        for (int it = 0; it < 32; it++) {
            int e = it * 256 + tid;
            int c = e >> 7, w = e & 127;
            lds[w * 65 + c] = xr[(size_t)c * HH * WW + w];
        }
        __syncthreads();
        unsigned* otr = (unsigned*)(xt + (size_t)bh * WW * CC);   // packed bf16 pairs
#pragma unroll
        for (int it = 0; it < 16; it++) {
            int e = it * 256 + tid;            // pair index: w*32 + cp
            int w = e >> 5, cp = e & 31;
            unsigned lo = (unsigned short)f2bf(lds[w * 65 + 2 * cp]);
            unsigned hi = (unsigned short)f2bf(lds[w * 65 + 2 * cp + 1]);
            otr[e] = lo | (hi << 16);
        }
    } else {
        int tid = (bid - BB * HH) * 256 + threadIdx.x;
        if (tid < 2 * 18 * 64 * 8) {                 // 18432
            int i = tid & 7, lane = (tid >> 3) & 63, ch = (tid >> 9) % 18, tile = tid / (18 * 512);
            int r = tile * 16 + (lane & 15);
            int q = ch * 32 + ((lane >> 4) << 3) + i;
            int k = q >> 6, c = q & 63;
            float v = 0.f;
            if (r < 18)      v = offset_w[(r * CC + c) * 9 + k];
            else if (r < 27) v = mask_w[((r - 18) * CC + c) * 9 + k];
            w1f[tid] = f2bf(v);
        } else {
            int u = tid - 18432;
            if (u < 4 * 18 * 64 * 8) {               // 36864
                int i = u & 7, lane = (u >> 3) & 63, ch = (u >> 9) % 18, tile = u / (18 * 512);
                int oc = tile * 16 + (lane & 15);
                int q = ch * 32 + ((lane >> 4) << 3) + i;
                int k = q >> 6, c = q & 63;
                w2f[u] = f2bf(weight[(oc * CC + c) * 9 + k]);
            }
        }
    }
}

// ---------------- K1: fused conv + deformable einsum, 2-row LDS window ----------------
// [R17 verified body — byte-for-byte revert; setprio and R18's duplicated
//  Phase-A load block removed]
__global__ __launch_bounds__(512, 4) void fused_mfma(
    const unsigned short* __restrict__ xt,
    const float* __restrict__ offset_b,
    const float* __restrict__ mask_b,
    const float* __restrict__ bias,
    const short* __restrict__ w1f,
    const short* __restrict__ w2f,
    float* __restrict__ out) {
    extern __shared__ __align__(16) char shbuf[];    // SH_TOTAL = 79104 B dynamic
    char* win = shbuf;
    float* wlds = (float*)(shbuf + WIN_BYTES);   // [pl][72]: 9 taps x {4 w, 4 off}
    float* colds = wlds;                         // overlaid [pl][33] (phase A only)

    int lane = threadIdx.x & 63;
    int wv = threadIdx.x >> 6;                    // 0..7
    int bid = blockIdx.x;
    int logical = (bid & 7) * 128 + (bid >> 3);   // XCD-chunked: bid%8 -> image
    int col = lane & 15;
    int qg = lane >> 4;
    int pl = wv * 16 + col;                       // 0..127
    int b = logical >> 7;
    int rem = logical & 127;
    int oh0 = (rem >> 1) << 1;                    // 2-row block
    int ow0 = (rem & 1) << 6;                     // 64-col half
    int oh = oh0 + (pl >> 6);
    int ow = ow0 + (pl & 63);
    const unsigned short* xb = xt + (size_t)b * CC * HH * WW;   // NHWC bf16

    int ylo = max(0, oh0 - 1), yhi = min(HH - 1, oh0 + 3);
    int xlo = max(0, ow0 - 1), xhi = min(WW - 1, ow0 + 64);
    int R = yhi - ylo + 1, C = xhi - xlo + 1;     // R<=5, C<=65

    // ---- Stage window: R x C pixels x 128B, coalesced in, swizzled to LDS
    {
        int C8 = C * 8;
        for (int ry = 0; ry < R; ry++) {
            const unsigned short* src = xb + ((size_t)(ylo + ry) * WW + xlo) * CC;
            for (int t = threadIdx.x; t < C8; t += 512) {
                int rx = t >> 3, s = t & 7;
                u32x4 v = *(const u32x4*)(src + rx * CC + s * 8);
                int pix = ry * WCOLS + rx;
                *(u32x4*)(win + (pix << 7) + ((s ^ (pix & 7)) << 4)) = v;
            }
        }
    }
    __syncthreads();

    // ---- Phase A: 3x3 conv -> 27 offset/mask channels (taps read from window)
    {
        f32x4 acc0 = {0.f,0.f,0.f,0.f}, acc1 = {0.f,0.f,0.f,0.f};
#pragma unroll
        for (int ch = 0; ch < 18; ch++) {
            int k = ch >> 1;
            int iy = oh - 1 + k / 3;
            int ix = ow - 1 + (k - (k / 3) * 3);
            bool vv = (iy >= 0) && (iy < HH) && (ix >= 0) && (ix < WW);
            bf16x8 bfr = {0,0,0,0,0,0,0,0};
            if (vv) {
                int pix = (iy - ylo) * WCOLS + (ix - xlo);
                int s = ((ch & 1) << 2) + qg;
                bfr = *(const bf16x8*)(win + (pix << 7) + ((s ^ (pix & 7)) << 4));
            }
            bf16x8 a0 = *(const bf16x8*)(w1f + ((size_t)(0 * 18 + ch) * 64 + lane) * 8);
            bf16x8 a1 = *(const bf16x8*)(w1f + ((size_t)(1 * 18 + ch) * 64 + lane) * 8);
            acc0 = __builtin_amdgcn_mfma_f32_16x16x32_bf16(a0, bfr, acc0, 0, 0, 0);
            acc1 = __builtin_amdgcn_mfma_f32_16x16x32_bf16(a1, bfr, acc1, 0, 0, 0);
        }
#pragma unroll
        for (int j = 0; j < 4; j++) {
            int r0 = (qg << 2) + j;
            int r1 = 16 + r0;
            float b1 = (r1 < 18) ? offset_b[r1] : (r1 < 27 ? mask_b[r1 - 18] : 0.f);
            colds[pl * 33 + r0] = acc0[j] + offset_b[r0];
            colds[pl * 33 + r1] = acc1[j] + b1;
        }
    }
    __syncthreads();

    // ---- Hoist (qg-split): taps k = qg, qg+4, qg+8; read colds now, store later
    float hw[3][4];
    unsigned ho[3][4];
    {
        const float* cop = &colds[pl * 33];
#pragma unroll
        for (int ki = 0; ki < 3; ki++) {
            int k = qg + ki * 4;
            if (k < 9) {
                float dy = cop[2 * k];
                float dx = cop[2 * k + 1];
                float mr = cop[18 + k];
                float m = 1.f / (1.f + __expf(-mr));
                float py = (float)(oh - 1 + k / 3) + dy;
                float px = (float)(ow - 1 + (k - (k / 3) * 3)) + dx;
                float y0f = floorf(py), x0f = floorf(px);
                float fy = py - y0f, fx = px - x0f;
                int y0 = (int)y0f, x0 = (int)x0f;
                int y1 = y0 + 1, x1 = x0 + 1;
                bool vy0 = (y0 >= 0) && (y0 < HH), vy1 = (y1 >= 0) && (y1 < HH);
                bool vx0 = (x0 >= 0) && (x0 < WW), vx1 = (x1 >= 0) && (x1 < WW);
                hw[ki][0] = (vy0 && vx0) ? (1.f - fy) * (1.f - fx) * m : 0.f;
                hw[ki][1] = (vy0 && vx1) ? (1.f - fy) * fx * m : 0.f;
                hw[ki][2] = (vy1 && vx0) ? fy * (1.f - fx) * m : 0.f;
                hw[ki][3] = (vy1 && vx1) ? fy * fx * m : 0.f;
                int iy0 = min(max(y0, 0), HH - 1), iy1 = min(max(y1, 0), HH - 1);
                int ix0 = min(max(x0, 0), WW - 1), ix1 = min(max(x1, 0), WW - 1);
                int wy0 = iy0 - ylo, wy1 = iy1 - ylo;
                int wx0 = ix0 - xlo, wx1 = ix1 - xlo;
                bool fast = (wy0 >= 0) && (wy1 < R) && (wx0 >= 0) && (wx1 < C);
                if (fast) {
                    ho[ki][0] = (unsigned)((wy0 * WCOLS + wx0) << 7);
                    ho[ki][1] = (unsigned)((wy0 * WCOLS + wx1) << 7);
                    ho[ki][2] = (unsigned)((wy1 * WCOLS + wx0) << 7);
                    ho[ki][3] = (unsigned)((wy1 * WCOLS + wx1) << 7);
                } else {
                    ho[ki][0] = (unsigned)((iy0 * WW + ix0) * CC) | 0x80000000u;
                    ho[ki][1] = (unsigned)((iy0 * WW + ix1) * CC) | 0x80000000u;
                    ho[ki][2] = (unsigned)((iy1 * WW + ix0) * CC) | 0x80000000u;
                    ho[ki][3] = (unsigned)((iy1 * WW + ix1) * CC) | 0x80000000u;
                }
            }
        }
    }
    __syncthreads();   // all colds reads done; safe to overwrite with wlds
#pragma unroll
    for (int ki = 0; ki < 3; ki++) {
        int k = qg + ki * 4;
        if (k < 9) {
            float* q = &wlds[pl * WLDS_STRIDE + k * 8];
            q[0] = hw[ki][0]; q[1] = hw[ki][1]; q[2] = hw[ki][2]; q[3] = hw[ki][3];
            ((unsigned*)q)[4] = ho[ki][0]; ((unsigned*)q)[5] = ho[ki][1];
            ((unsigned*)q)[6] = ho[ki][2]; ((unsigned*)q)[7] = ho[ki][3];
        }
    }
    __syncthreads();

    // ---- Phase B: 9 taps, corners from LDS window (outside-window -> global slow path)
    f32x4 acc0 = {0.f,0.f,0.f,0.f}, acc1 = {0.f,0.f,0.f,0.f};
    f32x4 acc2 = {0.f,0.f,0.f,0.f}, acc3 = {0.f,0.f,0.f,0.f};
    const float* wp = &wlds[pl * WLDS_STRIDE];
    const unsigned short* xq = xb + (qg << 3);
    unsigned sh0 = (unsigned)(qg << 4);
    unsigned sh1 = sh0 + 64;

#pragma unroll
    for (int k = 0; k < 9; k++) {
        f32x4 wq = *(const f32x4*)(wp + k * 8);
        u32x4 o = __builtin_bit_cast(u32x4, *(const f32x4*)(wp + k * 8 + 4));
        bf16x8 h0[4], h1[4];
        if (!(o[0] & 0x80000000u)) {
#pragma unroll
            for (int c = 0; c < 4; c++) {
                unsigned base = o[c];
                unsigned swz = (base >> 3) & 0x70;
                h0[c] = *(const bf16x8*)(win + base + (sh0 ^ swz));
                h1[c] = *(const bf16x8*)(win + base + (sh1 ^ swz));
            }
        } else {
#pragma unroll
            for (int c = 0; c < 4; c++) {
                unsigned off = o[c] & 0x7FFFFFFFu;
                h0[c] = *(const bf16x8*)(xq + off);
                h1[c] = *(const bf16x8*)(xq + off + 32);
            }
        }
        bf16x8 bf0 = bilerp8(h0[0], h0[1], h0[2], h0[3], wq);
        bf16x8 bf1 = bilerp8(h1[0], h1[1], h1[2], h1[3], wq);
#pragma unroll
        for (int h = 0; h < 2; h++) {
            bf16x8 bfr = h ? bf1 : bf0;
            int ch = 2 * k + h;
            const short* ap = w2f + ((size_t)ch * 64 + lane) * 8;
            bf16x8 a0 = *(const bf16x8*)(ap);
            bf16x8 a1 = *(const bf16x8*)(ap + 18 * 512);
            bf16x8 a2 = *(const bf16x8*)(ap + 36 * 512);
            bf16x8 a3 = *(const bf16x8*)(ap + 54 * 512);
            acc0 = __builtin_amdgcn_mfma_f32_16x16x32_bf16(a0, bfr, acc0, 0, 0, 0);
            acc1 = __builtin_amdgcn_mfma_f32_16x16x32_bf16(a1, bfr, acc1, 0, 0, 0);
            acc2 = __builtin_amdgcn_mfma_f32_16x16x32_bf16(a2, bfr, acc2, 0, 0, 0);
            acc3 = __builtin_amdgcn_mfma_f32_16x16x32_bf16(a3, bfr, acc3, 0, 0, 0);
        }
    }

    size_t ob = (size_t)b * OCC * HH * WW + (size_t)oh * WW + ow;
#pragma unroll
    for (int j = 0; j < 4; j++) {
        int r = (qg << 2) + j;
        out[ob + (size_t)r * HH * WW]        = acc0[j] + bias[r];
        out[ob + (size_t)(r + 16) * HH * WW] = acc1[j] + bias[r + 16];
        out[ob + (size_t)(r + 32) * HH * WW] = acc2[j] + bias[r + 32];
        out[ob + (size_t)(r + 48) * HH * WW] = acc3[j] + bias[r + 48];
    }
}

// ---------------- Fallback (round-1, all-f32, no ws) ----------------
__global__ __launch_bounds__(256)
void deform_fused_fb(const float* __restrict__ x,
                     const float* __restrict__ weight,
                     const float* __restrict__ bias,
                     const float* __restrict__ offset_w,
                     const float* __restrict__ offset_b,
                     const float* __restrict__ mask_w,
                     const float* __restrict__ mask_b,
                     float* __restrict__ out) {
    int p = blockIdx.x * 256 + threadIdx.x;
    int ow = p & (WW - 1);
    int oh = (p >> 7) & (HH - 1);
    int b = p >> 14;
    const float* xb = x + (size_t)b * CC * HH * WW;

    float acc[27];
#pragma unroll
    for (int j = 0; j < 18; j++) acc[j] = offset_b[j];
#pragma unroll
    for (int j = 0; j < 9; j++) acc[18 + j] = mask_b[j];

    for (int c = 0; c < CC; c++) {
        const float* xc = xb + c * HH * WW;
        float xv[9];
#pragma unroll
        for (int t = 0; t < 9; t++) {
            int iy = oh - 1 + t / 3;
            int ix = ow - 1 + t % 3;
            bool v = (iy >= 0) && (iy < HH) && (ix >= 0) && (ix < WW);
            xv[t] = v ? xc[iy * WW + ix] : 0.f;
        }
#pragma unroll
        for (int t = 0; t < 9; t++)
#pragma unroll
            for (int j = 0; j < 27; j++) {
                float wv = (j < 18) ? offset_w[(j * CC + c) * 9 + t]
                                    : mask_w[((j - 18) * CC + c) * 9 + t];
                acc[j] += xv[t] * wv;
            }
    }

    float acc2[OCC];
#pragma unroll
    for (int o = 0; o < OCC; o++) acc2[o] = 0.f;

#pragma unroll
    for (int k = 0; k < 9; k++) {
        float dy = acc[2 * k], dx = acc[2 * k + 1];
        float m = 1.f / (1.f + __expf(-acc[18 + k]));
        float py = (float)(oh - 1 + k / 3) + dy;
        float px = (float)(ow - 1 + k % 3) + dx;
        float y0f = floorf(py), x0f = floorf(px);
        float fy = py - y0f, fx = px - x0f;
        int y0 = (int)y0f, x0 = (int)x0f;
        int y1 = y0 + 1, x1 = x0 + 1;
        bool vy0 = (y0 >= 0) && (y0 < HH), vy1 = (y1 >= 0) && (y1 < HH);
        bool vx0 = (x0 >= 0) && (x0 < WW), vx1 = (x1 >= 0) && (x1 < WW);
        float w00 = (vy0 && vx0) ? (1.f - fy) * (1.f - fx) * m : 0.f;
        float w01 = (vy0 && vx1) ? (1.f - fy) * fx * m : 0.f;
        float w10 = (vy1 && vx0) ? fy * (1.f - fx) * m : 0.f;
        float w11 = (vy1 && vx1) ? fy * fx * m : 0.f;
        int iy0 = min(max(y0, 0), HH - 1), iy1 = min(max(y1, 0), HH - 1);
        int ix0 = min(max(x0, 0), WW - 1), ix1 = min(max(x1, 0), WW - 1);
        int o00 = iy0 * WW + ix0, o01 = iy0 * WW + ix1;
        int o10 = iy1 * WW + ix0, o11 = iy1 * WW + ix1;
        for (int c = 0; c < CC; c++) {
            const float* xc = xb + c * HH * WW;
            float v = w00 * xc[o00] + w01 * xc[o01] + w10 * xc[o10] + w11 * xc[o11];
#pragma unroll
            for (int o = 0; o < OCC; o++) acc2[o] += v * weight[(o * CC + c) * 9 + k];
        }
    }
    float* ob = out + (size_t)b * OCC * HH * WW + oh * WW + ow;
#pragma unroll
    for (int o = 0; o < OCC; o++) ob[(size_t)o * HH * WW] = acc2[o] + bias[o];
}

extern "C" void kernel_launch(void* const* d_in, const int* in_sizes, int n_in,
                              void* d_out, int out_size, void* d_ws, size_t ws_size,
                              hipStream_t stream) {
    const float* x        = (const float*)d_in[0];
    const float* weight   = (const float*)d_in[1];
    const float* bias     = (const float*)d_in[2];
    const float* offset_w = (const float*)d_in[3];
    const float* offset_b = (const float*)d_in[4];
    const float* mask_w   = (const float*)d_in[5];
    const float* mask_b   = (const float*)d_in[6];
    float* out = (float*)d_out;

    if (ws_size >= (size_t)WS_FULL) {
        unsigned short* xt = (unsigned short*)((char*)d_ws + XT_OFF);
        short* w1f = (short*)((char*)d_ws + W1F_OFF);
        short* w2f = (short*)((char*)d_ws + W2F_OFF);
        (void)hipFuncSetAttribute((const void*)fused_mfma,
                                  hipFuncAttributeMaxDynamicSharedMemorySize, SH_TOTAL);
        prep_and_transpose<<<BB * HH + 216, 256, 0, stream>>>(x, xt, weight, offset_w,
                                                              mask_w, w1f, w2f);
        fused_mfma<<<NPIX / PXB, 512, SH_TOTAL, stream>>>(xt, offset_b, mask_b, bias,
                                                          w1f, w2f, out);
    } else {
        deform_fused_fb<<<NPIX / 256, 256, 0, stream>>>(x, weight, bias, offset_w, offset_b,
                                                        mask_w, mask_b, out);
    }
}